// Round 19
// baseline (343.551 us; speedup 1.0000x reference)
//
#include <hip/hip_runtime.h>
#include <math.h>

// STN3d, B=32, C=3, N=4096. Training-mode BN (batch stats), moment-folded.
// 9 dispatches (no memsets):
//  kA_xpart (+ inits sum3/sq3/maxe/mine/gram) -> kC2_gram (atomic Gram) ->
//  kD_fold2 -> kE2_layer2 (FP16 frag-major h2t) ->
//  k5_layer3 (32x32x16 FP16 MFMA 2-term, 128-pt chunks, 2x32KB bufs) ->
//  k_fin3_pool -> fc1 -> fc2 -> k_tail3 (fc3 + Euler->R, single block).

#define EPS 1e-5f
#define PI_F 3.1415927410125732f

typedef unsigned int u32;
typedef unsigned short u16;
typedef _Float16 f16;
typedef __bf16 bf16x8 __attribute__((ext_vector_type(8)));
typedef f16 f16x8 __attribute__((ext_vector_type(8)));
typedef float f32x4 __attribute__((ext_vector_type(4)));
typedef float f32x16 __attribute__((ext_vector_type(16)));

#define AS1 __attribute__((address_space(1)))
#define AS3 __attribute__((address_space(3)))

__device__ __forceinline__ u16 f2bf(float f) {
  u32 u = __float_as_uint(f);
  return (u16)((u + 0x7FFFu + ((u >> 16) & 1u)) >> 16);
}
__device__ __forceinline__ float bf2f(u16 h) { return __uint_as_float(((u32)h) << 16); }
__device__ __forceinline__ u16 f2h(float f) {
  f16 h = (f16)f;
  union { f16 x; u16 u; } c; c.x = h; return c.u;
}
__device__ __forceinline__ u32 encf(float f) {
  u32 u = __float_as_uint(f);
  return (u & 0x80000000u) ? ~u : (u | 0x80000000u);
}
__device__ __forceinline__ float decf(u32 u) {
  return __uint_as_float((u & 0x80000000u) ? (u ^ 0x80000000u) : ~u);
}

// ---------------- kA: x second-moment partials + accumulator inits ----------------
__global__ __launch_bounds__(256) void kA_xpart(const float* __restrict__ x,
    float* __restrict__ xst_part,
    float* __restrict__ sum3, float* __restrict__ sq3,
    u32* __restrict__ maxe, u32* __restrict__ mine, float* __restrict__ gram) {
  __shared__ float wsum[4][9];
  int t = threadIdx.x;
  int tg = blockIdx.x * 256 + t;
  // accumulator inits (replaces 3 hipMemsetAsync dispatches)
  sum3[tg] = 0.f;
  sq3[tg] = 0.f;
  maxe[tg] = 0u;
  mine[tg] = 0xFFFFFFFFu;
  if (tg < 4160) gram[tg] = 0.f;
  int b = tg >> 10, nq = (tg & 1023) << 2;
  const float* xb = x + ((size_t)b * 3) * 4096 + nq;
  float4 a = *(const float4*)(xb);
  float4 c = *(const float4*)(xb + 4096);
  float4 d = *(const float4*)(xb + 8192);
  float p[9];
  p[0] = (a.x + a.y) + (a.z + a.w);
  p[1] = (c.x + c.y) + (c.z + c.w);
  p[2] = (d.x + d.y) + (d.z + d.w);
  p[3] = fmaf(a.x,a.x, fmaf(a.y,a.y, fmaf(a.z,a.z, a.w*a.w)));
  p[4] = fmaf(a.x,c.x, fmaf(a.y,c.y, fmaf(a.z,c.z, a.w*c.w)));
  p[5] = fmaf(a.x,d.x, fmaf(a.y,d.y, fmaf(a.z,d.z, a.w*d.w)));
  p[6] = fmaf(c.x,c.x, fmaf(c.y,c.y, fmaf(c.z,c.z, c.w*c.w)));
  p[7] = fmaf(c.x,d.x, fmaf(c.y,d.y, fmaf(c.z,d.z, c.w*d.w)));
  p[8] = fmaf(d.x,d.x, fmaf(d.y,d.y, fmaf(d.z,d.z, d.w*d.w)));
  #pragma unroll
  for (int k = 0; k < 9; ++k) {
    #pragma unroll
    for (int s = 1; s < 64; s <<= 1) p[k] += __shfl_xor(p[k], s);
  }
  if ((t & 63) == 0) {
    #pragma unroll
    for (int k = 0; k < 9; ++k) wsum[t >> 6][k] = p[k];
  }
  __syncthreads();
  if (t < 9) xst_part[blockIdx.x*9 + t] = wsum[0][t] + wsum[1][t] + wsum[2][t] + wsum[3][t];
}

// ---------------- kC2: fold1 (redundant) + MFMA Gram of h1 -> ATOMIC gram ---------
__global__ __launch_bounds__(256) void kC2_gram(const float* __restrict__ x,
    const float* __restrict__ xst_part,
    const float* __restrict__ w1, const float* __restrict__ b1,
    const float* __restrict__ g1, const float* __restrict__ be1,
    float* __restrict__ gram, float* __restrict__ w1f_g, float* __restrict__ b1f_g) {
  __shared__ float xsl[3][1024];
  __shared__ float4 w1s4[64];
  __shared__ __align__(16) char hfrag[4352];
  __shared__ __align__(16) char lfrag[4352];
  __shared__ float mred[256];
  __shared__ float xstL[9];
  int t = threadIdx.x, bi = blockIdx.x;
  int lane = t & 63, wid = t >> 6;
  if (t < 9) { float s = 0.f; for (int p = 0; p < 128; ++p) s += xst_part[p*9 + t]; xstL[t] = s; }
  int b = bi >> 2, n0 = (bi & 3) << 10;
  for (int i = t; i < 3072; i += 256) {
    int c = i >> 10, n = i & 1023;
    xsl[c][n] = x[((size_t)b*3 + c)*4096 + n0 + n];
  }
  __syncthreads();
  if (t < 64) {
    const float inv = 1.f/131072.f;
    float mx = xstL[0]*inv, my = xstL[1]*inv, mz = xstL[2]*inv;
    float cxx = xstL[3]*inv - mx*mx, cxy = xstL[4]*inv - mx*my, cxz = xstL[5]*inv - mx*mz;
    float cyy = xstL[6]*inv - my*my, cyz = xstL[7]*inv - my*mz, czz = xstL[8]*inv - mz*mz;
    float wa = w1[t*3], wb = w1[t*3+1], wc = w1[t*3+2];
    float mu = fmaf(wa, mx, fmaf(wb, my, fmaf(wc, mz, b1[t])));
    float var = wa*wa*cxx + wb*wb*cyy + wc*wc*czz
              + 2.f*(wa*wb*cxy + wa*wc*cxz + wb*wc*cyz);
    float s = g1[t] * rsqrtf(var + EPS);
    float bf = be1[t] + s*(b1[t] - mu);
    w1s4[t] = make_float4(s*wa, s*wb, s*wc, bf);
    if (bi == 0) { w1f_g[t*3] = s*wa; w1f_g[t*3+1] = s*wb; w1f_g[t*3+2] = s*wc; b1f_g[t] = bf; }
  }
  __syncthreads();
  int ch = t & 63, ptg = t >> 6;
  float4 wv = w1s4[ch];
  int wbyte = (ch >> 4)*1088 + (((ch & 15) | (ptg << 4)) << 4);
  const f32x4 zero4 = {0.f,0.f,0.f,0.f};
  f32x4 acc[4] = {zero4, zero4, zero4, zero4};
  float msum = 0.f;
  for (int it = 0; it < 32; ++it) {
    int p0 = (it << 5) | (ptg << 3);
    u32 hw[4], lw[4];
    #pragma unroll
    for (int q = 0; q < 4; ++q) {
      int pA = p0 + 2*q, pB = p0 + 2*q + 1;
      float v0 = fmaxf(fmaf(wv.x, xsl[0][pA], fmaf(wv.y, xsl[1][pA], fmaf(wv.z, xsl[2][pA], wv.w))), 0.f);
      float v1 = fmaxf(fmaf(wv.x, xsl[0][pB], fmaf(wv.y, xsl[1][pB], fmaf(wv.z, xsl[2][pB], wv.w))), 0.f);
      msum += v0 + v1;
      u16 h0 = f2bf(v0), h1 = f2bf(v1);
      hw[q] = (u32)h0 | ((u32)h1 << 16);
      lw[q] = (u32)f2bf(v0 - bf2f(h0)) | ((u32)f2bf(v1 - bf2f(h1)) << 16);
    }
    *(uint4*)(hfrag + wbyte) = make_uint4(hw[0],hw[1],hw[2],hw[3]);
    *(uint4*)(lfrag + wbyte) = make_uint4(lw[0],lw[1],lw[2],lw[3]);
    __syncthreads();
    bf16x8 ah = *(const bf16x8*)(hfrag + wid*1088 + (lane << 4));
    bf16x8 al = *(const bf16x8*)(lfrag + wid*1088 + (lane << 4));
    #pragma unroll
    for (int cg2 = 0; cg2 < 4; ++cg2) {
      bf16x8 bh = *(const bf16x8*)(hfrag + cg2*1088 + (lane << 4));
      bf16x8 bl = *(const bf16x8*)(lfrag + cg2*1088 + (lane << 4));
      acc[cg2] = __builtin_amdgcn_mfma_f32_16x16x32_bf16(al, bh, acc[cg2], 0, 0, 0);
      acc[cg2] = __builtin_amdgcn_mfma_f32_16x16x32_bf16(ah, bl, acc[cg2], 0, 0, 0);
      acc[cg2] = __builtin_amdgcn_mfma_f32_16x16x32_bf16(ah, bh, acc[cg2], 0, 0, 0);
    }
    __syncthreads();
  }
  mred[t] = msum;
  __syncthreads();
  if (t < 64)
    atomicAdd(&gram[4096 + t], mred[t] + mred[t+64] + mred[t+128] + mred[t+192]);
  #pragma unroll
  for (int cg2 = 0; cg2 < 4; ++cg2) {
    #pragma unroll
    for (int r = 0; r < 4; ++r) {
      int i = (wid << 4) | (((lane >> 4) << 2) | r);
      int j = (cg2 << 4) | (lane & 15);
      atomicAdd(&gram[i*64 + j], acc[cg2][r]);
    }
  }
}

// ---------------- kD: fold BN2 into W2 (reads reduced gram) -----------------------
__global__ __launch_bounds__(64) void kD_fold2(const float* __restrict__ gram,
    const float* __restrict__ w2, const float* __restrict__ b2,
    const float* __restrict__ g2, const float* __restrict__ be2,
    float* __restrict__ w2f, float* __restrict__ b2f) {
  __shared__ float wrow[64];
  int o = blockIdx.x, i = threadIdx.x;
  wrow[i] = w2[o*64 + i];
  __syncthreads();
  float si = 0.f;
  #pragma unroll 8
  for (int j = 0; j < 64; ++j) si = fmaf(wrow[j], gram[j*64 + i], si);
  const float inv = 1.f / 131072.f;
  float qi = wrow[i] * si;
  float di = wrow[i] * (gram[4096 + i] * inv);
  #pragma unroll
  for (int d2 = 1; d2 < 64; d2 <<= 1) { qi += __shfl_xor(qi, d2); di += __shfl_xor(di, d2); }
  float mu2 = di + b2[o];
  float var = qi*inv - di*di;
  float s = g2[o] * rsqrtf(var + EPS);
  w2f[o*64 + i] = s * wrow[i];
  if (i == 0) b2f[o] = be2[o] + s*(b2[o] - mu2);
}

// ---------------- kE2: layer2 bf16x3 MFMA -> relu -> FP16 frag-major h2t ----------
__global__ __launch_bounds__(256) void kE2_layer2(const float* __restrict__ x,
    const float* __restrict__ w1f, const float* __restrict__ b1f,
    const float* __restrict__ w2f, const float* __restrict__ b2f,
    u16* __restrict__ h2t) {
  __shared__ float xs[3][256];
  __shared__ float4 w1s4[64];
  __shared__ __align__(16) char h1h[17408];
  __shared__ __align__(16) char h1l[17408];
  int t = threadIdx.x;
  int b = ((blockIdx.x & 7) << 2) | ((blockIdx.x >> 3) & 3);
  int ntile = (blockIdx.x >> 5) << 8;
  int lane = t & 63, wid = t >> 6;
  int wo = wid & 1, wn = wid >> 1;
  #pragma unroll
  for (int i = 0; i < 3; ++i) {
    int idx = (i << 8) | t;
    int c = idx >> 8, n = idx & 255;
    xs[c][n] = x[((size_t)b*3 + c)*4096 + ntile + n];
  }
  if (t < 64) w1s4[t] = make_float4(w1f[t*3], w1f[t*3+1], w1f[t*3+2], b1f[t]);
  bf16x8 wf_hi[4][2], wf_lo[4][2];
  float4 bvv[4];
  #pragma unroll
  for (int of = 0; of < 4; ++of) {
    int o2r = (wo << 6) | (of << 4) | (lane & 15);
    bvv[of] = *(const float4*)(b2f + (wo << 6) + (of << 4) + ((lane >> 4) << 2));
    #pragma unroll
    for (int ks1 = 0; ks1 < 2; ++ks1) {
      const float* src = w2f + o2r*64 + (ks1 << 5) + ((lane >> 4) << 3);
      float4 f0 = *(const float4*)src;
      float4 f1 = *(const float4*)(src + 4);
      float fv[8] = {f0.x,f0.y,f0.z,f0.w, f1.x,f1.y,f1.z,f1.w};
      u32 hw[4], lw[4];
      #pragma unroll
      for (int p2 = 0; p2 < 4; ++p2) {
        u16 h0 = f2bf(fv[2*p2]), h1 = f2bf(fv[2*p2+1]);
        u16 l0 = f2bf(fv[2*p2] - bf2f(h0)), l1 = f2bf(fv[2*p2+1] - bf2f(h1));
        hw[p2] = (u32)h0 | ((u32)h1 << 16);
        lw[p2] = (u32)l0 | ((u32)l1 << 16);
      }
      uint4 H = make_uint4(hw[0],hw[1],hw[2],hw[3]);
      uint4 L = make_uint4(lw[0],lw[1],lw[2],lw[3]);
      wf_hi[of][ks1] = *(const bf16x8*)&H;
      wf_lo[of][ks1] = *(const bf16x8*)&L;
    }
  }
  __syncthreads();
  const f32x4 zero4 = {0.f,0.f,0.f,0.f};
  for (int chunk = 0; chunk < 2; ++chunk) {
    {
      int n = t >> 1, ks1 = t & 1;
      int nL = (chunk << 7) | n;
      float xa = xs[0][nL], xb = xs[1][nL], xc = xs[2][nL];
      int fb = (((n >> 4) << 1) | ks1) * 1088 + ((n & 15) << 4);
      #pragma unroll
      for (int kq = 0; kq < 4; ++kq) {
        u32 hw[4], lw[4];
        #pragma unroll
        for (int p2 = 0; p2 < 4; ++p2) {
          int k1 = (ks1 << 5) | (kq << 3) | (p2 << 1);
          float4 wv0 = w1s4[k1];
          float4 wv1 = w1s4[k1 + 1];
          float v0 = fmaxf(fmaf(wv0.x, xa, fmaf(wv0.y, xb, fmaf(wv0.z, xc, wv0.w))), 0.f);
          float v1 = fmaxf(fmaf(wv1.x, xa, fmaf(wv1.y, xb, fmaf(wv1.z, xc, wv1.w))), 0.f);
          u16 h0 = f2bf(v0), h1_ = f2bf(v1);
          hw[p2] = (u32)h0 | ((u32)h1_ << 16);
          lw[p2] = (u32)f2bf(v0 - bf2f(h0)) | ((u32)f2bf(v1 - bf2f(h1_)) << 16);
        }
        *(uint4*)(h1h + fb + (kq << 8)) = make_uint4(hw[0],hw[1],hw[2],hw[3]);
        *(uint4*)(h1l + fb + (kq << 8)) = make_uint4(lw[0],lw[1],lw[2],lw[3]);
      }
    }
    __syncthreads();
    #pragma unroll
    for (int nb = 0; nb < 4; ++nb) {
      int fbase = (((wn << 2) | nb) << 1) * 1088 + (lane << 4);
      bf16x8 bh0 = *(const bf16x8*)(h1h + fbase);
      bf16x8 bh1 = *(const bf16x8*)(h1h + fbase + 1088);
      bf16x8 bl0 = *(const bf16x8*)(h1l + fbase);
      bf16x8 bl1 = *(const bf16x8*)(h1l + fbase + 1088);
      int nblk_g = (ntile >> 4) | (chunk << 3) | (wn << 2) | nb;
      #pragma unroll
      for (int of = 0; of < 4; ++of) {
        f32x4 acc;
        acc = __builtin_amdgcn_mfma_f32_16x16x32_bf16(wf_hi[of][0], bl0, zero4, 0, 0, 0);
        acc = __builtin_amdgcn_mfma_f32_16x16x32_bf16(wf_lo[of][0], bh0, acc, 0, 0, 0);
        acc = __builtin_amdgcn_mfma_f32_16x16x32_bf16(wf_hi[of][0], bh0, acc, 0, 0, 0);
        acc = __builtin_amdgcn_mfma_f32_16x16x32_bf16(wf_hi[of][1], bl1, acc, 0, 0, 0);
        acc = __builtin_amdgcn_mfma_f32_16x16x32_bf16(wf_lo[of][1], bh1, acc, 0, 0, 0);
        acc = __builtin_amdgcn_mfma_f32_16x16x32_bf16(wf_hi[of][1], bh1, acc, 0, 0, 0);
        ushort4 hs;
        hs.x = f2h(fmaxf(acc[0] + bvv[of].x, 0.f));
        hs.y = f2h(fmaxf(acc[1] + bvv[of].y, 0.f));
        hs.z = f2h(fmaxf(acc[2] + bvv[of].z, 0.f));
        hs.w = f2h(fmaxf(acc[3] + bvv[of].w, 0.f));
        int ks2 = (wo << 1) | (of >> 1);
        int q = ((of & 1) << 1) | ((lane >> 5) & 1);
        int l = (lane & 15) | (q << 4);
        int j0 = ((lane >> 4) & 1) << 2;
        size_t idx = ((((size_t)((b << 8) | nblk_g) << 2) | ks2) << 9) + (l << 3) + j0;
        *(ushort4*)(h2t + idx) = hs;
      }
    }
    __syncthreads();
  }
}

// ---------------- k5: FP16 2-term MFMA 32x32x16, 128-pt chunks, 2x32KB bufs -------
__global__ __launch_bounds__(256, 2) void k5_layer3(
    const u16* __restrict__ h2t, const float* __restrict__ w3,
    float* __restrict__ sum3, float* __restrict__ sq3,
    u32* __restrict__ maxe, u32* __restrict__ mine) {
  __shared__ __align__(16) char smem[65536];
  const int t = threadIdx.x, lane = t & 63, wid = t >> 6;
  const int id = blockIdx.x;
  const int xcd = id & 7, rest = id >> 3;
  const int gq = rest & 15, otile = rest >> 4;
  const int g = (gq << 3) | xcd;
  const int b = g >> 2, q = g & 3;

  const size_t gbase = ((size_t)b << 19) | ((size_t)q << 17);   // u16 elems
  auto STAGE = [&](int c, int buf) {
    char* lb = smem + buf * 32768;
    size_t gb = gbase + ((size_t)c << 14);                      // 16384 u16 / chunk
    #pragma unroll
    for (int i = 0; i < 8; ++i) {
      int off = (i << 12) | (t << 4);
      __builtin_amdgcn_global_load_lds((const AS1 u32*)(h2t + gb + (off >> 1)),
          (AS3 u32*)(lb + off), 16, 0, 0);
    }
  };
  STAGE(0, 0); STAGE(1, 1);    // 16 loads in flight

  // W3 B-frags (fp16 hi+lo): o = lane&31, k = ks*16 + (lane>>5)*8 + j
  f16x8 wh[8], wl[8];
  {
    int o3 = (otile << 7) | (wid << 5) | (lane & 31);
    #pragma unroll
    for (int ks = 0; ks < 8; ++ks) {
      const float* src = w3 + (size_t)o3*128 + (ks << 4) + ((lane >> 5) << 3);
      float4 f0 = *(const float4*)src;
      float4 f1 = *(const float4*)(src + 4);
      float fv[8] = {f0.x,f0.y,f0.z,f0.w, f1.x,f1.y,f1.z,f1.w};
      f16x8 vh, vl;
      #pragma unroll
      for (int p2 = 0; p2 < 8; ++p2) {
        f16 hh = (f16)fv[p2];
        vh[p2] = hh;
        vl[p2] = (f16)(fv[p2] - (float)hh);
      }
      wh[ks] = vh;
      wl[ks] = vl;
    }
  }

  const int aoff = (((lane >> 4) & 1) << 12) | ((((lane & 15) | (((lane >> 5) & 1) << 4))) << 4);

  const f32x16 zero16 = {0.f,0.f,0.f,0.f,0.f,0.f,0.f,0.f,0.f,0.f,0.f,0.f,0.f,0.f,0.f,0.f};
  float rs = 0.f, rq = 0.f, rmx = -3.4e38f, rmn = 3.4e38f;

  for (int c = 0; c < 8; ++c) {
    if (c < 7) asm volatile("s_waitcnt vmcnt(8)" ::: "memory");
    else       asm volatile("s_waitcnt vmcnt(0)" ::: "memory");
    __builtin_amdgcn_s_barrier();
    const char* bp = smem + (c & 1) * 32768 + aoff;
    __builtin_amdgcn_s_setprio(1);
    #pragma unroll
    for (int nf = 0; nf < 4; ++nf) {
      const char* bn = bp + (nf << 13);
      f32x16 accA, accB;
      #pragma unroll
      for (int ks = 0; ks < 8; ++ks) {
        int ao = ((ks >> 1) << 10) | ((ks & 1) << 9);
        f16x8 av = *(const f16x8*)(bn + ao);
        accA = __builtin_amdgcn_mfma_f32_32x32x16_f16(av, wh[ks], ks ? accA : zero16, 0, 0, 0);
        accB = __builtin_amdgcn_mfma_f32_32x32x16_f16(av, wl[ks], ks ? accB : zero16, 0, 0, 0);
      }
      f32x16 acc = accA + accB;
      #pragma unroll
      for (int r = 0; r < 16; r += 4) {
        rs += ((acc[r] + acc[r+1]) + (acc[r+2] + acc[r+3]));
        rq = fmaf(acc[r],acc[r], fmaf(acc[r+1],acc[r+1],
             fmaf(acc[r+2],acc[r+2], fmaf(acc[r+3],acc[r+3], rq))));
        rmx = fmaxf(fmaxf(rmx, fmaxf(acc[r],acc[r+1])), fmaxf(acc[r+2],acc[r+3]));
        rmn = fminf(fminf(rmn, fminf(acc[r],acc[r+1])), fminf(acc[r+2],acc[r+3]));
      }
    }
    __builtin_amdgcn_s_setprio(0);
    __builtin_amdgcn_s_barrier();
    if (c < 6) STAGE(c + 2, c & 1);
  }

  rs += __shfl_xor(rs, 32);
  rq += __shfl_xor(rq, 32);
  rmx = fmaxf(rmx, __shfl_xor(rmx, 32));
  rmn = fminf(rmn, __shfl_xor(rmn, 32));
  if (lane < 32) {
    int go = (b << 10) | (otile << 7) | (wid << 5) | lane;
    atomicAdd(&sum3[go], rs);
    atomicAdd(&sq3[go], rq);
    atomicMax(&maxe[go], encf(rmx));
    atomicMin(&mine[go], encf(rmn));
  }
}

// ---------------- finalize stats3 (+bias fold) + pooled ---------------------------
__global__ void k_fin3_pool(const float* __restrict__ sum3, const float* __restrict__ sq3,
    const u32* __restrict__ maxe, const u32* __restrict__ mine,
    const float* __restrict__ b3,
    const float* __restrict__ g, const float* __restrict__ be, float* __restrict__ pool) {
  int o = blockIdx.x*256 + threadIdx.x;
  float S = 0.f, Q = 0.f;
  for (int b = 0; b < 32; ++b) { S += sum3[(b<<10)|o]; Q += sq3[(b<<10)|o]; }
  const float inv = 1.f/131072.f;
  float ma = S*inv;
  float m = ma + b3[o];
  float var = Q*inv - ma*ma;
  float sc = g[o]*rsqrtf(var + EPS);
  float sh = be[o] - sc*m;
  bool pos = (sc >= 0.f);
  for (int b = 0; b < 32; ++b) {
    float v = decf(pos ? maxe[(b<<10)|o] : mine[(b<<10)|o]) + b3[o];
    pool[(b<<10)|o] = fmaxf(fmaf(sc, v, sh), 0.f);
  }
}

// ---------------- fused FC + batch-BN + ReLU --------------------------------------
__global__ __launch_bounds__(256) void k_fc_bn_relu(const float* __restrict__ in,
    const float* __restrict__ w, const float* __restrict__ fb,
    const float* __restrict__ g, const float* __restrict__ be,
    float* __restrict__ out, int K, int F) {
  __shared__ float wrow[1024];
  __shared__ float preb[32];
  int o = blockIdx.x, t = threadIdx.x;
  for (int k = t; k < K; k += 256) wrow[k] = w[(size_t)o*K + k];
  __syncthreads();
  int b = t >> 3, j = t & 7;
  int per = K >> 3;
  const float* inb = in + (size_t)b*K + j*per;
  const float* wp  = wrow + j*per;
  float p = 0.f;
  for (int k = 0; k < per; ++k) p = fmaf(inb[k], wp[k], p);
  p += __shfl_xor(p, 1); p += __shfl_xor(p, 2); p += __shfl_xor(p, 4);
  if (j == 0) preb[b] = p + fb[o];
  __syncthreads();
  if (t < 32) {
    float v = preb[t];
    float s = v;
    #pragma unroll
    for (int d = 1; d < 32; d <<= 1) s += __shfl_xor(s, d);
    float m = s * 0.03125f;
    float dv = v - m;
    float q = dv*dv;
    #pragma unroll
    for (int d = 1; d < 32; d <<= 1) q += __shfl_xor(q, d);
    float var = q * 0.03125f;
    float sc = g[o]*rsqrtf(var + EPS);
    out[(size_t)t*F + o] = fmaxf(fmaf(sc, dv, be[o]), 0.f);
  }
}

// ---------------- k_tail3: fc3 (4 o/iter, wave-synchronous) + Euler->R ------------
// Single block, 256 threads (4 waves). No __syncthreads inside the fc3 loop.
__global__ __launch_bounds__(256) void k_tail3(const float* __restrict__ h5v,
    const float* __restrict__ fw3, const float* __restrict__ fb3,
    const float* __restrict__ g6, const float* __restrict__ be6,
    const float* __restrict__ fw4, const float* __restrict__ fb4,
    float* __restrict__ out) {
  __shared__ float h6s[32][128];
  __shared__ float angs[32][3];
  int t = threadIdx.x, lane = t & 63, wid = t >> 6;
  int b = lane >> 1, j = lane & 1;
  for (int o0 = 0; o0 < 128; o0 += 4) {
    int o = o0 + wid;
    const float* inb = h5v + b*256 + j*128;
    const float* wp  = fw3 + (size_t)o*256 + j*128;
    float p = 0.f;
    #pragma unroll 8
    for (int k = 0; k < 128; ++k) p = fmaf(inb[k], wp[k], p);
    p += __shfl_xor(p, 1);                  // combine j halves; both lanes hold dot(b)
    float pp = p + fb3[o];
    float v = __shfl(pp, (lane & 31) << 1); // lane i <- value for batch i
    float s = v;
    #pragma unroll
    for (int d = 1; d < 32; d <<= 1) s += __shfl_xor(s, d);
    float m = s * 0.03125f;
    float dv = v - m;
    float q2 = dv*dv;
    #pragma unroll
    for (int d = 1; d < 32; d <<= 1) q2 += __shfl_xor(q2, d);
    float var = q2 * 0.03125f;
    float sc = g6[o]*rsqrtf(var + EPS);
    if (lane < 32) h6s[lane][o] = fmaxf(fmaf(sc, dv, be6[o]), 0.f);
  }
  __syncthreads();
  if (t < 96) {
    int bb = t / 3, jj = t % 3;
    float p = 0.f;
    #pragma unroll 4
    for (int k = 0; k < 128; ++k) p = fmaf(h6s[bb][k], fw4[jj*128 + k], p);
    angs[bb][jj] = (p + fb4[jj]) * PI_F;
  }
  __syncthreads();
  if (t < 32) {
    float a = angs[t][0], bb = angs[t][1], c = angs[t][2];
    float sa, ca; sincosf(a,  &sa, &ca);
    float sb, cb; sincosf(bb, &sb, &cb);
    float sc, cc; sincosf(c,  &sc, &cc);
    float* o9 = out + t*9;
    o9[0] = cc*cb;
    o9[1] = fmaf(cc*sb, sa, -sc*ca);
    o9[2] = fmaf(cc*sb, ca,  sc*sa);
    o9[3] = sc*cb;
    o9[4] = fmaf(sc*sb, sa,  cc*ca);
    o9[5] = fmaf(sc*sb, ca, -cc*sa);
    o9[6] = -sb;
    o9[7] = cb*sa;
    o9[8] = cb*ca;
  }
}

extern "C" void kernel_launch(void* const* d_in, const int* in_sizes, int n_in,
                              void* d_out, int out_size, void* d_ws, size_t ws_size,
                              hipStream_t stream) {
  (void)in_sizes; (void)n_in; (void)out_size; (void)ws_size;
  const float* x   = (const float*)d_in[0];
  const float* w1  = (const float*)d_in[1];
  const float* b1  = (const float*)d_in[2];
  const float* g1  = (const float*)d_in[3];
  const float* be1 = (const float*)d_in[4];
  const float* w2  = (const float*)d_in[5];
  const float* b2  = (const float*)d_in[6];
  const float* g2  = (const float*)d_in[7];
  const float* be2 = (const float*)d_in[8];
  const float* w3  = (const float*)d_in[9];
  const float* b3  = (const float*)d_in[10];
  const float* g3  = (const float*)d_in[11];
  const float* be3 = (const float*)d_in[12];
  const float* fw1 = (const float*)d_in[13];
  const float* fb1 = (const float*)d_in[14];
  const float* g4  = (const float*)d_in[15];
  const float* be4 = (const float*)d_in[16];
  const float* fw2 = (const float*)d_in[17];
  const float* fb2 = (const float*)d_in[18];
  const float* g5p = (const float*)d_in[19];
  const float* be5 = (const float*)d_in[20];
  const float* fw3 = (const float*)d_in[21];
  const float* fb3 = (const float*)d_in[22];
  const float* g6  = (const float*)d_in[23];
  const float* be6 = (const float*)d_in[24];
  const float* fw4 = (const float*)d_in[25];
  const float* fb4 = (const float*)d_in[26];

  u16* h2t = (u16*)d_ws;                        // 32 MiB (fp16, frag-major)
  float* acc0 = (float*)d_ws + 8388608;         // after the fp16 plane (32 MiB)
  float* xst_part = acc0;                       // 1152
  float* w1f  = acc0 + 1152;                    // 192
  float* b1f  = acc0 + 1344;                    // 64
  float* w2f  = acc0 + 1408;                    // 8192
  float* b2f  = acc0 + 9600;                    // 128
  float* gram = acc0 + 9728;                    // 4160 (atomic-accumulated)
  float* sum3 = acc0 + 13888;                   // 32768
  float* sq3  = acc0 + 46656;                   // 32768
  u32*   maxe = (u32*)(acc0 + 79424);           // 32768
  u32*   mine = (u32*)(acc0 + 112192);          // 32768
  float* pool = acc0 + 144960;                  // 32768
  float* h4v  = acc0 + 177728;                  // 16384
  float* h5v  = acc0 + 194112;                  // 8192

  kA_xpart<<<128, 256, 0, stream>>>(x, xst_part, sum3, sq3, maxe, mine, gram);
  kC2_gram<<<128, 256, 0, stream>>>(x, xst_part, w1, b1, g1, be1, gram, w1f, b1f);
  kD_fold2<<<128, 64, 0, stream>>>(gram, w2, b2, g2, be2, w2f, b2f);
  kE2_layer2<<<512, 256, 0, stream>>>(x, w1f, b1f, w2f, b2f, h2t);
  k5_layer3<<<1024, 256, 0, stream>>>(h2t, w3, sum3, sq3, maxe, mine);
  k_fin3_pool<<<4, 256, 0, stream>>>(sum3, sq3, maxe, mine, b3, g3, be3, pool);
  k_fc_bn_relu<<<512, 256, 0, stream>>>(pool, fw1, fb1, g4, be4, h4v, 1024, 512);
  k_fc_bn_relu<<<256, 256, 0, stream>>>(h4v, fw2, fb2, g5p, be5, h5v, 512, 256);
  k_tail3<<<1, 256, 0, stream>>>(h5v, fw3, fb3, g6, be6, fw4, fb4, (float*)d_out);
}

// Round 20
// 161.777 us; speedup vs baseline: 2.1236x; 2.1236x over previous
//
#include <hip/hip_runtime.h>
#include <math.h>

// STN3d, B=32, C=3, N=4096. Training-mode BN (batch stats), moment-folded.
// 10 dispatches (no memsets):
//  kA_xpart (+ inits sum3/sq3/maxe/mine/gram) -> kC2_gram (atomic Gram) ->
//  kD_fold2 -> kE2_layer2 (FP16 frag-major h2t) ->
//  k5_layer3 (32x32x16 FP16 MFMA 2-term, 128-pt chunks, 2x32KB bufs) ->
//  k_fin3_pool -> fc1 -> fc2 -> fc3 -> k_final.

#define EPS 1e-5f
#define PI_F 3.1415927410125732f

typedef unsigned int u32;
typedef unsigned short u16;
typedef _Float16 f16;
typedef __bf16 bf16x8 __attribute__((ext_vector_type(8)));
typedef f16 f16x8 __attribute__((ext_vector_type(8)));
typedef float f32x4 __attribute__((ext_vector_type(4)));
typedef float f32x16 __attribute__((ext_vector_type(16)));

#define AS1 __attribute__((address_space(1)))
#define AS3 __attribute__((address_space(3)))

__device__ __forceinline__ u16 f2bf(float f) {
  u32 u = __float_as_uint(f);
  return (u16)((u + 0x7FFFu + ((u >> 16) & 1u)) >> 16);
}
__device__ __forceinline__ float bf2f(u16 h) { return __uint_as_float(((u32)h) << 16); }
__device__ __forceinline__ u16 f2h(float f) {
  f16 h = (f16)f;
  union { f16 x; u16 u; } c; c.x = h; return c.u;
}
__device__ __forceinline__ u32 encf(float f) {
  u32 u = __float_as_uint(f);
  return (u & 0x80000000u) ? ~u : (u | 0x80000000u);
}
__device__ __forceinline__ float decf(u32 u) {
  return __uint_as_float((u & 0x80000000u) ? (u ^ 0x80000000u) : ~u);
}

// ---------------- kA: x second-moment partials + accumulator inits ----------------
__global__ __launch_bounds__(256) void kA_xpart(const float* __restrict__ x,
    float* __restrict__ xst_part,
    float* __restrict__ sum3, float* __restrict__ sq3,
    u32* __restrict__ maxe, u32* __restrict__ mine, float* __restrict__ gram) {
  __shared__ float wsum[4][9];
  int t = threadIdx.x;
  int tg = blockIdx.x * 256 + t;
  sum3[tg] = 0.f;
  sq3[tg] = 0.f;
  maxe[tg] = 0u;
  mine[tg] = 0xFFFFFFFFu;
  if (tg < 4160) gram[tg] = 0.f;
  int b = tg >> 10, nq = (tg & 1023) << 2;
  const float* xb = x + ((size_t)b * 3) * 4096 + nq;
  float4 a = *(const float4*)(xb);
  float4 c = *(const float4*)(xb + 4096);
  float4 d = *(const float4*)(xb + 8192);
  float p[9];
  p[0] = (a.x + a.y) + (a.z + a.w);
  p[1] = (c.x + c.y) + (c.z + c.w);
  p[2] = (d.x + d.y) + (d.z + d.w);
  p[3] = fmaf(a.x,a.x, fmaf(a.y,a.y, fmaf(a.z,a.z, a.w*a.w)));
  p[4] = fmaf(a.x,c.x, fmaf(a.y,c.y, fmaf(a.z,c.z, a.w*c.w)));
  p[5] = fmaf(a.x,d.x, fmaf(a.y,d.y, fmaf(a.z,d.z, a.w*d.w)));
  p[6] = fmaf(c.x,c.x, fmaf(c.y,c.y, fmaf(c.z,c.z, c.w*c.w)));
  p[7] = fmaf(c.x,d.x, fmaf(c.y,d.y, fmaf(c.z,d.z, c.w*d.w)));
  p[8] = fmaf(d.x,d.x, fmaf(d.y,d.y, fmaf(d.z,d.z, d.w*d.w)));
  #pragma unroll
  for (int k = 0; k < 9; ++k) {
    #pragma unroll
    for (int s = 1; s < 64; s <<= 1) p[k] += __shfl_xor(p[k], s);
  }
  if ((t & 63) == 0) {
    #pragma unroll
    for (int k = 0; k < 9; ++k) wsum[t >> 6][k] = p[k];
  }
  __syncthreads();
  if (t < 9) xst_part[blockIdx.x*9 + t] = wsum[0][t] + wsum[1][t] + wsum[2][t] + wsum[3][t];
}

// ---------------- kC2: fold1 (redundant) + MFMA Gram of h1 -> ATOMIC gram ---------
__global__ __launch_bounds__(256) void kC2_gram(const float* __restrict__ x,
    const float* __restrict__ xst_part,
    const float* __restrict__ w1, const float* __restrict__ b1,
    const float* __restrict__ g1, const float* __restrict__ be1,
    float* __restrict__ gram, float* __restrict__ w1f_g, float* __restrict__ b1f_g) {
  __shared__ float xsl[3][1024];
  __shared__ float4 w1s4[64];
  __shared__ __align__(16) char hfrag[4352];
  __shared__ __align__(16) char lfrag[4352];
  __shared__ float mred[256];
  __shared__ float xstL[9];
  int t = threadIdx.x, bi = blockIdx.x;
  int lane = t & 63, wid = t >> 6;
  if (t < 9) { float s = 0.f; for (int p = 0; p < 128; ++p) s += xst_part[p*9 + t]; xstL[t] = s; }
  int b = bi >> 2, n0 = (bi & 3) << 10;
  for (int i = t; i < 3072; i += 256) {
    int c = i >> 10, n = i & 1023;
    xsl[c][n] = x[((size_t)b*3 + c)*4096 + n0 + n];
  }
  __syncthreads();
  if (t < 64) {
    const float inv = 1.f/131072.f;
    float mx = xstL[0]*inv, my = xstL[1]*inv, mz = xstL[2]*inv;
    float cxx = xstL[3]*inv - mx*mx, cxy = xstL[4]*inv - mx*my, cxz = xstL[5]*inv - mx*mz;
    float cyy = xstL[6]*inv - my*my, cyz = xstL[7]*inv - my*mz, czz = xstL[8]*inv - mz*mz;
    float wa = w1[t*3], wb = w1[t*3+1], wc = w1[t*3+2];
    float mu = fmaf(wa, mx, fmaf(wb, my, fmaf(wc, mz, b1[t])));
    float var = wa*wa*cxx + wb*wb*cyy + wc*wc*czz
              + 2.f*(wa*wb*cxy + wa*wc*cxz + wb*wc*cyz);
    float s = g1[t] * rsqrtf(var + EPS);
    float bf = be1[t] + s*(b1[t] - mu);
    w1s4[t] = make_float4(s*wa, s*wb, s*wc, bf);
    if (bi == 0) { w1f_g[t*3] = s*wa; w1f_g[t*3+1] = s*wb; w1f_g[t*3+2] = s*wc; b1f_g[t] = bf; }
  }
  __syncthreads();
  int ch = t & 63, ptg = t >> 6;
  float4 wv = w1s4[ch];
  int wbyte = (ch >> 4)*1088 + (((ch & 15) | (ptg << 4)) << 4);
  const f32x4 zero4 = {0.f,0.f,0.f,0.f};
  f32x4 acc[4] = {zero4, zero4, zero4, zero4};
  float msum = 0.f;
  for (int it = 0; it < 32; ++it) {
    int p0 = (it << 5) | (ptg << 3);
    u32 hw[4], lw[4];
    #pragma unroll
    for (int q = 0; q < 4; ++q) {
      int pA = p0 + 2*q, pB = p0 + 2*q + 1;
      float v0 = fmaxf(fmaf(wv.x, xsl[0][pA], fmaf(wv.y, xsl[1][pA], fmaf(wv.z, xsl[2][pA], wv.w))), 0.f);
      float v1 = fmaxf(fmaf(wv.x, xsl[0][pB], fmaf(wv.y, xsl[1][pB], fmaf(wv.z, xsl[2][pB], wv.w))), 0.f);
      msum += v0 + v1;
      u16 h0 = f2bf(v0), h1 = f2bf(v1);
      hw[q] = (u32)h0 | ((u32)h1 << 16);
      lw[q] = (u32)f2bf(v0 - bf2f(h0)) | ((u32)f2bf(v1 - bf2f(h1)) << 16);
    }
    *(uint4*)(hfrag + wbyte) = make_uint4(hw[0],hw[1],hw[2],hw[3]);
    *(uint4*)(lfrag + wbyte) = make_uint4(lw[0],lw[1],lw[2],lw[3]);
    __syncthreads();
    bf16x8 ah = *(const bf16x8*)(hfrag + wid*1088 + (lane << 4));
    bf16x8 al = *(const bf16x8*)(lfrag + wid*1088 + (lane << 4));
    #pragma unroll
    for (int cg2 = 0; cg2 < 4; ++cg2) {
      bf16x8 bh = *(const bf16x8*)(hfrag + cg2*1088 + (lane << 4));
      bf16x8 bl = *(const bf16x8*)(lfrag + cg2*1088 + (lane << 4));
      acc[cg2] = __builtin_amdgcn_mfma_f32_16x16x32_bf16(al, bh, acc[cg2], 0, 0, 0);
      acc[cg2] = __builtin_amdgcn_mfma_f32_16x16x32_bf16(ah, bl, acc[cg2], 0, 0, 0);
      acc[cg2] = __builtin_amdgcn_mfma_f32_16x16x32_bf16(ah, bh, acc[cg2], 0, 0, 0);
    }
    __syncthreads();
  }
  mred[t] = msum;
  __syncthreads();
  if (t < 64)
    atomicAdd(&gram[4096 + t], mred[t] + mred[t+64] + mred[t+128] + mred[t+192]);
  #pragma unroll
  for (int cg2 = 0; cg2 < 4; ++cg2) {
    #pragma unroll
    for (int r = 0; r < 4; ++r) {
      int i = (wid << 4) | (((lane >> 4) << 2) | r);
      int j = (cg2 << 4) | (lane & 15);
      atomicAdd(&gram[i*64 + j], acc[cg2][r]);
    }
  }
}

// ---------------- kD: fold BN2 into W2 (reads reduced gram) -----------------------
__global__ __launch_bounds__(64) void kD_fold2(const float* __restrict__ gram,
    const float* __restrict__ w2, const float* __restrict__ b2,
    const float* __restrict__ g2, const float* __restrict__ be2,
    float* __restrict__ w2f, float* __restrict__ b2f) {
  __shared__ float wrow[64];
  int o = blockIdx.x, i = threadIdx.x;
  wrow[i] = w2[o*64 + i];
  __syncthreads();
  float si = 0.f;
  #pragma unroll 8
  for (int j = 0; j < 64; ++j) si = fmaf(wrow[j], gram[j*64 + i], si);
  const float inv = 1.f / 131072.f;
  float qi = wrow[i] * si;
  float di = wrow[i] * (gram[4096 + i] * inv);
  #pragma unroll
  for (int d2 = 1; d2 < 64; d2 <<= 1) { qi += __shfl_xor(qi, d2); di += __shfl_xor(di, d2); }
  float mu2 = di + b2[o];
  float var = qi*inv - di*di;
  float s = g2[o] * rsqrtf(var + EPS);
  w2f[o*64 + i] = s * wrow[i];
  if (i == 0) b2f[o] = be2[o] + s*(b2[o] - mu2);
}

// ---------------- kE2: layer2 bf16x3 MFMA -> relu -> FP16 frag-major h2t ----------
__global__ __launch_bounds__(256) void kE2_layer2(const float* __restrict__ x,
    const float* __restrict__ w1f, const float* __restrict__ b1f,
    const float* __restrict__ w2f, const float* __restrict__ b2f,
    u16* __restrict__ h2t) {
  __shared__ float xs[3][256];
  __shared__ float4 w1s4[64];
  __shared__ __align__(16) char h1h[17408];
  __shared__ __align__(16) char h1l[17408];
  int t = threadIdx.x;
  int b = ((blockIdx.x & 7) << 2) | ((blockIdx.x >> 3) & 3);
  int ntile = (blockIdx.x >> 5) << 8;
  int lane = t & 63, wid = t >> 6;
  int wo = wid & 1, wn = wid >> 1;
  #pragma unroll
  for (int i = 0; i < 3; ++i) {
    int idx = (i << 8) | t;
    int c = idx >> 8, n = idx & 255;
    xs[c][n] = x[((size_t)b*3 + c)*4096 + ntile + n];
  }
  if (t < 64) w1s4[t] = make_float4(w1f[t*3], w1f[t*3+1], w1f[t*3+2], b1f[t]);
  bf16x8 wf_hi[4][2], wf_lo[4][2];
  float4 bvv[4];
  #pragma unroll
  for (int of = 0; of < 4; ++of) {
    int o2r = (wo << 6) | (of << 4) | (lane & 15);
    bvv[of] = *(const float4*)(b2f + (wo << 6) + (of << 4) + ((lane >> 4) << 2));
    #pragma unroll
    for (int ks1 = 0; ks1 < 2; ++ks1) {
      const float* src = w2f + o2r*64 + (ks1 << 5) + ((lane >> 4) << 3);
      float4 f0 = *(const float4*)src;
      float4 f1 = *(const float4*)(src + 4);
      float fv[8] = {f0.x,f0.y,f0.z,f0.w, f1.x,f1.y,f1.z,f1.w};
      u32 hw[4], lw[4];
      #pragma unroll
      for (int p2 = 0; p2 < 4; ++p2) {
        u16 h0 = f2bf(fv[2*p2]), h1 = f2bf(fv[2*p2+1]);
        u16 l0 = f2bf(fv[2*p2] - bf2f(h0)), l1 = f2bf(fv[2*p2+1] - bf2f(h1));
        hw[p2] = (u32)h0 | ((u32)h1 << 16);
        lw[p2] = (u32)l0 | ((u32)l1 << 16);
      }
      uint4 H = make_uint4(hw[0],hw[1],hw[2],hw[3]);
      uint4 L = make_uint4(lw[0],lw[1],lw[2],lw[3]);
      wf_hi[of][ks1] = *(const bf16x8*)&H;
      wf_lo[of][ks1] = *(const bf16x8*)&L;
    }
  }
  __syncthreads();
  const f32x4 zero4 = {0.f,0.f,0.f,0.f};
  for (int chunk = 0; chunk < 2; ++chunk) {
    {
      int n = t >> 1, ks1 = t & 1;
      int nL = (chunk << 7) | n;
      float xa = xs[0][nL], xb = xs[1][nL], xc = xs[2][nL];
      int fb = (((n >> 4) << 1) | ks1) * 1088 + ((n & 15) << 4);
      #pragma unroll
      for (int kq = 0; kq < 4; ++kq) {
        u32 hw[4], lw[4];
        #pragma unroll
        for (int p2 = 0; p2 < 4; ++p2) {
          int k1 = (ks1 << 5) | (kq << 3) | (p2 << 1);
          float4 wv0 = w1s4[k1];
          float4 wv1 = w1s4[k1 + 1];
          float v0 = fmaxf(fmaf(wv0.x, xa, fmaf(wv0.y, xb, fmaf(wv0.z, xc, wv0.w))), 0.f);
          float v1 = fmaxf(fmaf(wv1.x, xa, fmaf(wv1.y, xb, fmaf(wv1.z, xc, wv1.w))), 0.f);
          u16 h0 = f2bf(v0), h1_ = f2bf(v1);
          hw[p2] = (u32)h0 | ((u32)h1_ << 16);
          lw[p2] = (u32)f2bf(v0 - bf2f(h0)) | ((u32)f2bf(v1 - bf2f(h1_)) << 16);
        }
        *(uint4*)(h1h + fb + (kq << 8)) = make_uint4(hw[0],hw[1],hw[2],hw[3]);
        *(uint4*)(h1l + fb + (kq << 8)) = make_uint4(lw[0],lw[1],lw[2],lw[3]);
      }
    }
    __syncthreads();
    #pragma unroll
    for (int nb = 0; nb < 4; ++nb) {
      int fbase = (((wn << 2) | nb) << 1) * 1088 + (lane << 4);
      bf16x8 bh0 = *(const bf16x8*)(h1h + fbase);
      bf16x8 bh1 = *(const bf16x8*)(h1h + fbase + 1088);
      bf16x8 bl0 = *(const bf16x8*)(h1l + fbase);
      bf16x8 bl1 = *(const bf16x8*)(h1l + fbase + 1088);
      int nblk_g = (ntile >> 4) | (chunk << 3) | (wn << 2) | nb;
      #pragma unroll
      for (int of = 0; of < 4; ++of) {
        f32x4 acc;
        acc = __builtin_amdgcn_mfma_f32_16x16x32_bf16(wf_hi[of][0], bl0, zero4, 0, 0, 0);
        acc = __builtin_amdgcn_mfma_f32_16x16x32_bf16(wf_lo[of][0], bh0, acc, 0, 0, 0);
        acc = __builtin_amdgcn_mfma_f32_16x16x32_bf16(wf_hi[of][0], bh0, acc, 0, 0, 0);
        acc = __builtin_amdgcn_mfma_f32_16x16x32_bf16(wf_hi[of][1], bl1, acc, 0, 0, 0);
        acc = __builtin_amdgcn_mfma_f32_16x16x32_bf16(wf_lo[of][1], bh1, acc, 0, 0, 0);
        acc = __builtin_amdgcn_mfma_f32_16x16x32_bf16(wf_hi[of][1], bh1, acc, 0, 0, 0);
        ushort4 hs;
        hs.x = f2h(fmaxf(acc[0] + bvv[of].x, 0.f));
        hs.y = f2h(fmaxf(acc[1] + bvv[of].y, 0.f));
        hs.z = f2h(fmaxf(acc[2] + bvv[of].z, 0.f));
        hs.w = f2h(fmaxf(acc[3] + bvv[of].w, 0.f));
        int ks2 = (wo << 1) | (of >> 1);
        int q = ((of & 1) << 1) | ((lane >> 5) & 1);
        int l = (lane & 15) | (q << 4);
        int j0 = ((lane >> 4) & 1) << 2;
        size_t idx = ((((size_t)((b << 8) | nblk_g) << 2) | ks2) << 9) + (l << 3) + j0;
        *(ushort4*)(h2t + idx) = hs;
      }
    }
    __syncthreads();
  }
}

// ---------------- k5: FP16 2-term MFMA 32x32x16, 128-pt chunks, 2x32KB bufs -------
__global__ __launch_bounds__(256, 2) void k5_layer3(
    const u16* __restrict__ h2t, const float* __restrict__ w3,
    float* __restrict__ sum3, float* __restrict__ sq3,
    u32* __restrict__ maxe, u32* __restrict__ mine) {
  __shared__ __align__(16) char smem[65536];
  const int t = threadIdx.x, lane = t & 63, wid = t >> 6;
  const int id = blockIdx.x;
  const int xcd = id & 7, rest = id >> 3;
  const int gq = rest & 15, otile = rest >> 4;
  const int g = (gq << 3) | xcd;
  const int b = g >> 2, q = g & 3;

  const size_t gbase = ((size_t)b << 19) | ((size_t)q << 17);   // u16 elems
  auto STAGE = [&](int c, int buf) {
    char* lb = smem + buf * 32768;
    size_t gb = gbase + ((size_t)c << 14);                      // 16384 u16 / chunk
    #pragma unroll
    for (int i = 0; i < 8; ++i) {
      int off = (i << 12) | (t << 4);
      __builtin_amdgcn_global_load_lds((const AS1 u32*)(h2t + gb + (off >> 1)),
          (AS3 u32*)(lb + off), 16, 0, 0);
    }
  };
  STAGE(0, 0); STAGE(1, 1);    // 16 loads in flight

  // W3 B-frags (fp16 hi+lo): o = lane&31, k = ks*16 + (lane>>5)*8 + j
  f16x8 wh[8], wl[8];
  {
    int o3 = (otile << 7) | (wid << 5) | (lane & 31);
    #pragma unroll
    for (int ks = 0; ks < 8; ++ks) {
      const float* src = w3 + (size_t)o3*128 + (ks << 4) + ((lane >> 5) << 3);
      float4 f0 = *(const float4*)src;
      float4 f1 = *(const float4*)(src + 4);
      float fv[8] = {f0.x,f0.y,f0.z,f0.w, f1.x,f1.y,f1.z,f1.w};
      f16x8 vh, vl;
      #pragma unroll
      for (int p2 = 0; p2 < 8; ++p2) {
        f16 hh = (f16)fv[p2];
        vh[p2] = hh;
        vl[p2] = (f16)(fv[p2] - (float)hh);
      }
      wh[ks] = vh;
      wl[ks] = vl;
    }
  }

  const int aoff = (((lane >> 4) & 1) << 12) | ((((lane & 15) | (((lane >> 5) & 1) << 4))) << 4);

  const f32x16 zero16 = {0.f,0.f,0.f,0.f,0.f,0.f,0.f,0.f,0.f,0.f,0.f,0.f,0.f,0.f,0.f,0.f};
  float rs = 0.f, rq = 0.f, rmx = -3.4e38f, rmn = 3.4e38f;

  for (int c = 0; c < 8; ++c) {
    if (c < 7) asm volatile("s_waitcnt vmcnt(8)" ::: "memory");
    else       asm volatile("s_waitcnt vmcnt(0)" ::: "memory");
    __builtin_amdgcn_s_barrier();
    const char* bp = smem + (c & 1) * 32768 + aoff;
    __builtin_amdgcn_s_setprio(1);
    #pragma unroll
    for (int nf = 0; nf < 4; ++nf) {
      const char* bn = bp + (nf << 13);
      f32x16 accA, accB;
      #pragma unroll
      for (int ks = 0; ks < 8; ++ks) {
        int ao = ((ks >> 1) << 10) | ((ks & 1) << 9);
        f16x8 av = *(const f16x8*)(bn + ao);
        accA = __builtin_amdgcn_mfma_f32_32x32x16_f16(av, wh[ks], ks ? accA : zero16, 0, 0, 0);
        accB = __builtin_amdgcn_mfma_f32_32x32x16_f16(av, wl[ks], ks ? accB : zero16, 0, 0, 0);
      }
      f32x16 acc = accA + accB;
      #pragma unroll
      for (int r = 0; r < 16; r += 4) {
        rs += ((acc[r] + acc[r+1]) + (acc[r+2] + acc[r+3]));
        rq = fmaf(acc[r],acc[r], fmaf(acc[r+1],acc[r+1],
             fmaf(acc[r+2],acc[r+2], fmaf(acc[r+3],acc[r+3], rq))));
        rmx = fmaxf(fmaxf(rmx, fmaxf(acc[r],acc[r+1])), fmaxf(acc[r+2],acc[r+3]));
        rmn = fminf(fminf(rmn, fminf(acc[r],acc[r+1])), fminf(acc[r+2],acc[r+3]));
      }
    }
    __builtin_amdgcn_s_setprio(0);
    __builtin_amdgcn_s_barrier();
    if (c < 6) STAGE(c + 2, c & 1);
  }

  rs += __shfl_xor(rs, 32);
  rq += __shfl_xor(rq, 32);
  rmx = fmaxf(rmx, __shfl_xor(rmx, 32));
  rmn = fminf(rmn, __shfl_xor(rmn, 32));
  if (lane < 32) {
    int go = (b << 10) | (otile << 7) | (wid << 5) | lane;
    atomicAdd(&sum3[go], rs);
    atomicAdd(&sq3[go], rq);
    atomicMax(&maxe[go], encf(rmx));
    atomicMin(&mine[go], encf(rmn));
  }
}

// ---------------- finalize stats3 (+bias fold) + pooled ---------------------------
__global__ void k_fin3_pool(const float* __restrict__ sum3, const float* __restrict__ sq3,
    const u32* __restrict__ maxe, const u32* __restrict__ mine,
    const float* __restrict__ b3,
    const float* __restrict__ g, const float* __restrict__ be, float* __restrict__ pool) {
  int o = blockIdx.x*256 + threadIdx.x;
  float S = 0.f, Q = 0.f;
  for (int b = 0; b < 32; ++b) { S += sum3[(b<<10)|o]; Q += sq3[(b<<10)|o]; }
  const float inv = 1.f/131072.f;
  float ma = S*inv;
  float m = ma + b3[o];
  float var = Q*inv - ma*ma;
  float sc = g[o]*rsqrtf(var + EPS);
  float sh = be[o] - sc*m;
  bool pos = (sc >= 0.f);
  for (int b = 0; b < 32; ++b) {
    float v = decf(pos ? maxe[(b<<10)|o] : mine[(b<<10)|o]) + b3[o];
    pool[(b<<10)|o] = fmaxf(fmaf(sc, v, sh), 0.f);
  }
}

// ---------------- fused FC + batch-BN + ReLU --------------------------------------
__global__ __launch_bounds__(256) void k_fc_bn_relu(const float* __restrict__ in,
    const float* __restrict__ w, const float* __restrict__ fb,
    const float* __restrict__ g, const float* __restrict__ be,
    float* __restrict__ out, int K, int F) {
  __shared__ float wrow[1024];
  __shared__ float preb[32];
  int o = blockIdx.x, t = threadIdx.x;
  for (int k = t; k < K; k += 256) wrow[k] = w[(size_t)o*K + k];
  __syncthreads();
  int b = t >> 3, j = t & 7;
  int per = K >> 3;
  const float* inb = in + (size_t)b*K + j*per;
  const float* wp  = wrow + j*per;
  float p = 0.f;
  for (int k = 0; k < per; ++k) p = fmaf(inb[k], wp[k], p);
  p += __shfl_xor(p, 1); p += __shfl_xor(p, 2); p += __shfl_xor(p, 4);
  if (j == 0) preb[b] = p + fb[o];
  __syncthreads();
  if (t < 32) {
    float v = preb[t];
    float s = v;
    #pragma unroll
    for (int d = 1; d < 32; d <<= 1) s += __shfl_xor(s, d);
    float m = s * 0.03125f;
    float dv = v - m;
    float q = dv*dv;
    #pragma unroll
    for (int d = 1; d < 32; d <<= 1) q += __shfl_xor(q, d);
    float var = q * 0.03125f;
    float sc = g[o]*rsqrtf(var + EPS);
    out[(size_t)t*F + o] = fmaxf(fmaf(sc, dv, be[o]), 0.f);
  }
}

// ---------------- angles + Euler->rotation ----------------------------------------
__global__ __launch_bounds__(128) void k_final(const float* __restrict__ h6,
    const float* __restrict__ fw4, const float* __restrict__ fb4, float* __restrict__ out) {
  __shared__ float angs[32][3];
  int t = threadIdx.x;
  if (t < 96) {
    int b = t / 3, j = t % 3;
    float p = 0.f;
    #pragma unroll 4
    for (int k = 0; k < 128; ++k) p = fmaf(h6[b*128+k], fw4[j*128+k], p);
    angs[b][j] = (p + fb4[j]) * PI_F;
  }
  __syncthreads();
  if (t < 32) {
    float a = angs[t][0], bb = angs[t][1], c = angs[t][2];
    float sa, ca; sincosf(a,  &sa, &ca);
    float sb, cb; sincosf(bb, &sb, &cb);
    float sc, cc; sincosf(c,  &sc, &cc);
    float* o9 = out + t*9;
    o9[0] = cc*cb;
    o9[1] = fmaf(cc*sb, sa, -sc*ca);
    o9[2] = fmaf(cc*sb, ca,  sc*sa);
    o9[3] = sc*cb;
    o9[4] = fmaf(sc*sb, sa,  cc*ca);
    o9[5] = fmaf(sc*sb, ca, -cc*sa);
    o9[6] = -sb;
    o9[7] = cb*sa;
    o9[8] = cb*ca;
  }
}

extern "C" void kernel_launch(void* const* d_in, const int* in_sizes, int n_in,
                              void* d_out, int out_size, void* d_ws, size_t ws_size,
                              hipStream_t stream) {
  (void)in_sizes; (void)n_in; (void)out_size; (void)ws_size;
  const float* x   = (const float*)d_in[0];
  const float* w1  = (const float*)d_in[1];
  const float* b1  = (const float*)d_in[2];
  const float* g1  = (const float*)d_in[3];
  const float* be1 = (const float*)d_in[4];
  const float* w2  = (const float*)d_in[5];
  const float* b2  = (const float*)d_in[6];
  const float* g2  = (const float*)d_in[7];
  const float* be2 = (const float*)d_in[8];
  const float* w3  = (const float*)d_in[9];
  const float* b3  = (const float*)d_in[10];
  const float* g3  = (const float*)d_in[11];
  const float* be3 = (const float*)d_in[12];
  const float* fw1 = (const float*)d_in[13];
  const float* fb1 = (const float*)d_in[14];
  const float* g4  = (const float*)d_in[15];
  const float* be4 = (const float*)d_in[16];
  const float* fw2 = (const float*)d_in[17];
  const float* fb2 = (const float*)d_in[18];
  const float* g5p = (const float*)d_in[19];
  const float* be5 = (const float*)d_in[20];
  const float* fw3 = (const float*)d_in[21];
  const float* fb3 = (const float*)d_in[22];
  const float* g6  = (const float*)d_in[23];
  const float* be6 = (const float*)d_in[24];
  const float* fw4 = (const float*)d_in[25];
  const float* fb4 = (const float*)d_in[26];

  u16* h2t = (u16*)d_ws;                        // 32 MiB (fp16, frag-major)
  float* acc0 = (float*)d_ws + 8388608;         // after the fp16 plane (32 MiB)
  float* xst_part = acc0;                       // 1152
  float* w1f  = acc0 + 1152;                    // 192
  float* b1f  = acc0 + 1344;                    // 64
  float* w2f  = acc0 + 1408;                    // 8192
  float* b2f  = acc0 + 9600;                    // 128
  float* gram = acc0 + 9728;                    // 4160 (atomic-accumulated)
  float* sum3 = acc0 + 13888;                   // 32768
  float* sq3  = acc0 + 46656;                   // 32768
  u32*   maxe = (u32*)(acc0 + 79424);           // 32768
  u32*   mine = (u32*)(acc0 + 112192);          // 32768
  float* pool = acc0 + 144960;                  // 32768
  float* h4v  = acc0 + 177728;                  // 16384
  float* h5v  = acc0 + 194112;                  // 8192
  float* h6v  = acc0 + 202304;                  // 4096

  kA_xpart<<<128, 256, 0, stream>>>(x, xst_part, sum3, sq3, maxe, mine, gram);
  kC2_gram<<<128, 256, 0, stream>>>(x, xst_part, w1, b1, g1, be1, gram, w1f, b1f);
  kD_fold2<<<128, 64, 0, stream>>>(gram, w2, b2, g2, be2, w2f, b2f);
  kE2_layer2<<<512, 256, 0, stream>>>(x, w1f, b1f, w2f, b2f, h2t);
  k5_layer3<<<1024, 256, 0, stream>>>(h2t, w3, sum3, sq3, maxe, mine);
  k_fin3_pool<<<4, 256, 0, stream>>>(sum3, sq3, maxe, mine, b3, g3, be3, pool);
  k_fc_bn_relu<<<512, 256, 0, stream>>>(pool, fw1, fb1, g4, be4, h4v, 1024, 512);
  k_fc_bn_relu<<<256, 256, 0, stream>>>(h4v, fw2, fb2, g5p, be5, h5v, 512, 256);
  k_fc_bn_relu<<<128, 256, 0, stream>>>(h5v, fw3, fb3, g6, be6, h6v, 256, 128);
  k_final<<<1, 128, 0, stream>>>(h6v, fw4, fb4, (float*)d_out);
}